// Round 11
// baseline (20244.391 us; speedup 1.0000x reference)
//
#include <hip/hip_runtime.h>
#include <math.h>

// ---------------------------------------------------------------------------
// CurvePredictor R11: deep batches x 2 waves/SIMD.
// R7 (8 waves, 128 VGPR) and R10 (4 waves, 200 VGPR) both pin at ~62 GB/s/CU
// weight pull -> rate invariant to TLP alone or ILP alone. This round has
// BOTH: 64 blocks x 512 threads (2 waves/SIMD) with R10's 2x16-frag double
// batches (~220 VGPR/wave, fits the 256 structural cap; LDS kept at 141KB so
// the occupancy heuristic cannot clamp VGPR to 128 for 2-blocks/CU).
// Wave w owns 2 hidden 16-col slices; c-state in LDS; xp streamed from d_ws;
// weight loads nontemporal (zero L1 reuse in the stream).
// Double-buffered h0/h1 in LDS, 3 barriers/step, zero cross-block sync.
// ---------------------------------------------------------------------------

typedef short s8v __attribute__((ext_vector_type(8)));   // 8 x bf16
typedef float f4v __attribute__((ext_vector_type(4)));   // 4 x f32

#define HSTR 264            // LDS h-row stride in shorts (33*16B)
#define DSTR 136
#define XP_OFF 2166784u     // byte offset of xp scratch in d_ws

__device__ __forceinline__ f4v mfma16(s8v a, s8v b, f4v c){
  return __builtin_amdgcn_mfma_f32_16x16x32_bf16(a, b, c, 0, 0, 0);
}
__device__ __forceinline__ short f2bf(float f){
  unsigned u = __float_as_uint(f);
  u = u + 0x7FFFu + ((u >> 16) & 1u);
  return (short)(u >> 16);
}
__device__ __forceinline__ float wred(float v){
  #pragma unroll
  for (int o = 32; o; o >>= 1) v += __shfl_xor(v, o);
  return v;
}
__device__ __forceinline__ float sigm(float x){ return 1.0f / (1.0f + __expf(-x)); }
__device__ __forceinline__ float tnh(float x){
  x = fminf(15.0f, fmaxf(-15.0f, x));
  float e = __expf(2.0f * x);
  return (e - 1.0f) / (e + 1.0f);
}
__device__ __forceinline__ float gelu(float v){
  return 0.5f * v * (1.0f + erff(v * 0.70710678118654752440f));
}

// ws layout (shorts), swizzled (same as R5-R10):
// main matrices (1024x256): elem = s*16384 + g*4096 + kk*512 + lane*8 + j
//   [0,262144) Wih0  [262144,524288) Whh0  [524288,786432) Wih1  [786432,1048576) Whh1
// W3 [128][256]: 1048576 + s2*4096 + kk*512 + lane*8
// W4 padded [16][128]: 1081344 + kk*512 + lane*8
// then at byte XP_OFF: f32 xp scratch, 128KB per block.
__global__ void prep_kernel(
    const float* __restrict__ Wih0, const float* __restrict__ Whh0,
    const float* __restrict__ Wih1, const float* __restrict__ Whh1,
    const float* __restrict__ W3,   const float* __restrict__ W4,
    short* __restrict__ wsb)
{
  const int i = blockIdx.x * 256 + threadIdx.x;
  if (i >= 1083392) return;
  float v;
  if (i < 1048576){
    const int seg = i >> 18;
    const int r   = i & 262143;
    const int s   = r >> 14;
    const int g   = (r >> 12) & 3;
    const int kk  = (r >> 9) & 7;
    const int q   = (r >> 7) & 3;
    const int m16 = (r >> 3) & 15;
    const int j   = r & 7;
    const int hid = s * 16 + m16;
    const int k   = kk * 32 + q * 8 + j;
    const float* mt = (seg == 0) ? Wih0 : (seg == 1) ? Whh0 : (seg == 2) ? Wih1 : Whh1;
    v = mt[(g * 256 + hid) * 256 + k];
  } else if (i < 1081344){
    const int r   = i - 1048576;
    const int s2  = r >> 12;
    const int kk  = (r >> 9) & 7;
    const int q   = (r >> 7) & 3;
    const int m16 = (r >> 3) & 15;
    const int j   = r & 7;
    v = W3[(s2 * 16 + m16) * 256 + kk * 32 + q * 8 + j];
  } else {
    const int r   = i - 1081344;
    const int kk  = (r >> 9) & 3;
    const int q   = (r >> 7) & 3;
    const int m16 = (r >> 3) & 15;
    const int j   = r & 7;
    const int k   = kk * 32 + q * 8 + j;
    v = (m16 < 2) ? W4[m16 * 128 + k] : 0.0f;
  }
  wsb[i] = f2bf(v);
}

// Load one 16-frag half-batch (4 kk x 4 gates) into registers (nontemporal).
__device__ __forceinline__ void load16(s8v* B, const short* __restrict__ pw, int half){
  #pragma unroll
  for (int f = 0; f < 16; f++)
    B[f] = __builtin_nontemporal_load(
              (const s8v*)(pw + (f & 3) * 4096 + (half * 4 + (f >> 2)) * 512));
}
// Consume it: 32 MFMAs (2 row-tiles).
__device__ __forceinline__ void consume16(const s8v* B, const short* __restrict__ hA,
                                          int kk0, int m16, int q, f4v (&acc)[2][4]){
  #pragma unroll
  for (int kx = 0; kx < 4; kx++){
    const int kk = kk0 + kx;
    const s8v a0 = *(const s8v*)&hA[ m16       * HSTR + kk * 32 + q * 8];
    const s8v a1 = *(const s8v*)&hA[(16 + m16) * HSTR + kk * 32 + q * 8];
    #pragma unroll
    for (int g = 0; g < 4; g++){
      acc[0][g] = mfma16(a0, B[kx * 4 + g], acc[0][g]);
      acc[1][g] = mfma16(a1, B[kx * 4 + g], acc[1][g]);
    }
  }
}

__global__ __launch_bounds__(512, 1) void curve_main(
    const float* __restrict__ x,
    const float* __restrict__ W1, const float* __restrict__ b1,
    const float* __restrict__ g1, const float* __restrict__ be1,
    const float* __restrict__ W2, const float* __restrict__ b2,
    const float* __restrict__ g2, const float* __restrict__ be2,
    const float* __restrict__ bih0, const float* __restrict__ bhh0,
    const float* __restrict__ bih1, const float* __restrict__ bhh1,
    const float* __restrict__ b3, const float* __restrict__ b4,
    const short* __restrict__ wsb, float* __restrict__ xpg,
    float* __restrict__ out)
{
  const int tid  = threadIdx.x;
  const int w    = tid >> 6;        // wave 0..7, owns slices {2w, 2w+1}
  const int lane = tid & 63;
  const int q    = lane >> 4;
  const int m16  = lane & 15;
  const int row0 = blockIdx.x * 32;

  __shared__ __align__(16) short h0b[2][32 * HSTR];
  __shared__ __align__(16) short h1b[2][32 * HSTR];
  __shared__ __align__(16) short dstg[32 * DSTR];
  __shared__ __align__(16) float csh[32 * 512];   // c-state: idx*512 + tid

  // --------- encoder: wave w computes batch rows row0 + u*8 + w ------------
  #pragma unroll 1
  for (int u = 0; u < 4; u++){
    const int rr = u * 8 + w;
    const int r  = row0 + rr;
    float xv[5];
    #pragma unroll
    for (int k = 0; k < 5; k++) xv[k] = x[r * 5 + k];
    float a0 = b1[lane], a1 = b1[lane + 64];
    #pragma unroll
    for (int k = 0; k < 5; k++){
      a0 += xv[k] * W1[lane * 5 + k];
      a1 += xv[k] * W1[(lane + 64) * 5 + k];
    }
    a0 = gelu(a0); a1 = gelu(a1);
    float mean = wred(a0 + a1) * (1.0f / 128.0f);
    float d0 = a0 - mean, d1 = a1 - mean;
    float inv = rsqrtf(wred(d0 * d0 + d1 * d1) * (1.0f / 128.0f) + 1e-5f);
    float y0 = d0 * inv * g1[lane]      + be1[lane];
    float y1 = d1 * inv * g1[lane + 64] + be1[lane + 64];

    float acc2[4];
    #pragma unroll
    for (int uu = 0; uu < 4; uu++) acc2[uu] = b2[lane + 64 * uu];
    for (int k = 0; k < 64; k++){
      float v0 = __shfl(y0, k);
      float v1 = __shfl(y1, k);
      #pragma unroll
      for (int uu = 0; uu < 4; uu++){
        const float* wr = W2 + (lane + 64 * uu) * 128;
        acc2[uu] += v0 * wr[k] + v1 * wr[k + 64];
      }
    }
    #pragma unroll
    for (int uu = 0; uu < 4; uu++) acc2[uu] = gelu(acc2[uu]);
    float s = acc2[0] + acc2[1] + acc2[2] + acc2[3];
    mean = wred(s) * (1.0f / 256.0f);
    float vv = 0.0f;
    #pragma unroll
    for (int uu = 0; uu < 4; uu++){ float d = acc2[uu] - mean; vv += d * d; }
    inv = rsqrtf(wred(vv) * (1.0f / 256.0f) + 1e-5f);
    #pragma unroll
    for (int uu = 0; uu < 4; uu++){
      int c = lane + 64 * uu;
      float e = (acc2[uu] - mean) * inv * g2[c] + be2[c];
      h0b[0][rr * HSTR + c] = f2bf(e);       // enc staged in h0 slot 0
    }
  }
  __syncthreads();

  // swizzled bases for this wave (slice stride 16384 shorts), lane offset incl.
  const short* pwi0 = wsb            + (2 * w) * 16384 + (lane << 3);
  const short* pwh0 = wsb +  262144  + (2 * w) * 16384 + (lane << 3);
  const short* pwi1 = wsb +  524288  + (2 * w) * 16384 + (lane << 3);
  const short* pwh1 = wsb +  786432  + (2 * w) * 16384 + (lane << 3);
  const short* pw3  = wsb + 1048576  + w * 4096 + (lane << 3);
  const short* pw4  = wsb + 1081344  + (lane << 3);
  float* xpw = xpg + blockIdx.x * 32768 + (2 * w) * 2048 + lane * 4;

  // ---- init: xp = enc @ Wih0^T + (bih0+bhh0) -> f32 scratch in d_ws ----
  #pragma unroll 1
  for (int s = 0; s < 2; s++){
    const short* pw = pwi0 + s * 16384;
    s8v P[16], Q[16];
    load16(P, pw, 0);
    load16(Q, pw, 1);
    f4v acc[2][4];
    #pragma unroll
    for (int g = 0; g < 4; g++){
      const int n = g * 256 + (2 * w + s) * 16 + m16;
      const float bi = bih0[n] + bhh0[n];
      f4v t = {bi, bi, bi, bi};
      acc[0][g] = t; acc[1][g] = t;
    }
    consume16(P, &h0b[0][0], 0, m16, q, acc);
    consume16(Q, &h0b[0][0], 4, m16, q, acc);
    float* xs = xpw + s * 2048;
    #pragma unroll
    for (int rt = 0; rt < 2; rt++)
      #pragma unroll
      for (int g = 0; g < 4; g++){
        float4 v4 = {acc[rt][g][0], acc[rt][g][1], acc[rt][g][2], acc[rt][g][3]};
        *(float4*)(xs + (rt * 4 + g) * 256) = v4;
      }
  }
  __syncthreads();
  for (int i = tid; i < 32 * HSTR; i += 512){ h0b[0][i] = 0; h1b[0][i] = 0; }
  for (int i = tid; i < 32 * 512; i += 512) csh[i] = 0.0f;

  // register-resident decoder constants
  s8v w4f[4];
  #pragma unroll
  for (int kk = 0; kk < 4; kk++) w4f[kk] = *(const s8v*)(pw4 + kk * 512);
  const float b3c = b3[w * 16 + m16];
  const float b4v = (m16 < 2) ? b4[m16] : 0.0f;
  __syncthreads();

  // --------------------------- recurrence over T ---------------------------
  #pragma unroll 1
  for (int t = 0; t < 256; t++){
    const short* h0in  = h0b[t & 1];
    short*       h0out = h0b[(t + 1) & 1];
    const short* h1in  = h1b[t & 1];
    short*       h1out = h1b[(t + 1) & 1];

    // ---- Phase A: gates0 = xp + h0_old @ Whh0^T -> c0 (LDS), h0_new ----
    #pragma unroll 1
    for (int s = 0; s < 2; s++){
      const short* pw = pwh0 + s * 16384;
      const float* xs = xpw + s * 2048;
      float4 xf[8];
      #pragma unroll
      for (int j = 0; j < 8; j++) xf[j] = *(const float4*)(xs + j * 256);
      s8v P[16], Q[16];
      load16(P, pw, 0);
      load16(Q, pw, 1);
      f4v acc[2][4];
      #pragma unroll
      for (int rt = 0; rt < 2; rt++)
        #pragma unroll
        for (int g = 0; g < 4; g++){
          const float4 v4 = xf[rt * 4 + g];
          f4v tv = {v4.x, v4.y, v4.z, v4.w};
          acc[rt][g] = tv;
        }
      consume16(P, h0in, 0, m16, q, acc);
      consume16(Q, h0in, 4, m16, q, acc);
      const int col = (2 * w + s) * 16 + m16;
      float* cp = &csh[(s * 8) * 512 + tid];
      #pragma unroll
      for (int rt = 0; rt < 2; rt++)
        #pragma unroll
        for (int r = 0; r < 4; r++){
          float cc = cp[(rt * 4 + r) * 512];
          float ii = sigm(acc[rt][0][r]);
          float ff = sigm(acc[rt][1][r]);
          float gg = tnh (acc[rt][2][r]);
          float oo = sigm(acc[rt][3][r]);
          cc = ff * cc + ii * gg;
          cp[(rt * 4 + r) * 512] = cc;
          h0out[(rt * 16 + q * 4 + r) * HSTR + col] = f2bf(oo * tnh(cc));
        }
    }
    __syncthreads();                             // (1) h0_new visible

    // ---- Phase B: gates1 = bias1 + h0_new@Wih1^T + h1_old@Whh1^T ----
    #pragma unroll 1
    for (int s = 0; s < 2; s++){
      const short* pi = pwi1 + s * 16384;
      const short* ph = pwh1 + s * 16384;
      const int col = (2 * w + s) * 16 + m16;
      s8v P[16], Q[16];
      load16(P, pi, 0);
      load16(Q, pi, 1);
      f4v acc[2][4];
      #pragma unroll
      for (int g = 0; g < 4; g++){
        const int n = g * 256 + col;
        const float bi = bih1[n] + bhh1[n];
        f4v tv = {bi, bi, bi, bi};
        acc[0][g] = tv; acc[1][g] = tv;
      }
      consume16(P, h0out, 0, m16, q, acc);
      load16(P, ph, 0);
      consume16(Q, h0out, 4, m16, q, acc);
      load16(Q, ph, 1);
      consume16(P, h1in, 0, m16, q, acc);
      consume16(Q, h1in, 4, m16, q, acc);
      float* cp = &csh[(16 + s * 8) * 512 + tid];
      #pragma unroll
      for (int rt = 0; rt < 2; rt++)
        #pragma unroll
        for (int r = 0; r < 4; r++){
          float cc = cp[(rt * 4 + r) * 512];
          float ii = sigm(acc[rt][0][r]);
          float ff = sigm(acc[rt][1][r]);
          float gg = tnh (acc[rt][2][r]);
          float oo = sigm(acc[rt][3][r]);
          cc = ff * cc + ii * gg;
          cp[(rt * 4 + r) * 512] = cc;
          h1out[(rt * 16 + q * 4 + r) * HSTR + col] = f2bf(oo * tnh(cc));
        }
    }
    __syncthreads();                             // (2) h1_new visible

    // ---- Phase C: d = gelu(h1_new @ W3^T + b3); wave w -> cg = w ----
    {
      s8v W3b[8];
      #pragma unroll
      for (int f = 0; f < 8; f++)
        W3b[f] = __builtin_nontemporal_load((const s8v*)(pw3 + f * 512));
      #pragma unroll
      for (int rt = 0; rt < 2; rt++){
        f4v ad = {b3c, b3c, b3c, b3c};
        #pragma unroll
        for (int kk = 0; kk < 8; kk++){
          const s8v a = *(const s8v*)&h1out[(rt * 16 + m16) * HSTR + kk * 32 + q * 8];
          ad = mfma16(a, W3b[kk], ad);
        }
        #pragma unroll
        for (int r = 0; r < 4; r++)
          dstg[(rt * 16 + q * 4 + r) * DSTR + w * 16 + m16] = f2bf(gelu(ad[r]));
      }
    }
    __syncthreads();                             // (3) d visible

    // ---- Phase D: out = d @ W4^T + b4 (waves 0,1; rt = w) ----
    if (w < 2){
      const int rt = w;
      f4v ao = {0.f, 0.f, 0.f, 0.f};
      #pragma unroll
      for (int kk = 0; kk < 4; kk++){
        const s8v a = *(const s8v*)&dstg[(rt * 16 + m16) * DSTR + kk * 32 + q * 8];
        ao = mfma16(a, w4f[kk], ao);
      }
      if (m16 < 2){
        #pragma unroll
        for (int r = 0; r < 4; r++)
          out[((size_t)(row0 + rt * 16 + q * 4 + r) * 256 + t) * 2 + m16] = ao[r] + b4v;
      }
    }
  }
}

extern "C" void kernel_launch(void* const* d_in, const int* in_sizes, int n_in,
                              void* d_out, int out_size, void* d_ws, size_t ws_size,
                              hipStream_t stream)
{
  const float* x    = (const float*)d_in[0];
  const float* W1   = (const float*)d_in[1];
  const float* b1   = (const float*)d_in[2];
  const float* g1   = (const float*)d_in[3];
  const float* be1  = (const float*)d_in[4];
  const float* W2   = (const float*)d_in[5];
  const float* b2   = (const float*)d_in[6];
  const float* g2   = (const float*)d_in[7];
  const float* be2  = (const float*)d_in[8];
  const float* Wih0 = (const float*)d_in[9];
  const float* Whh0 = (const float*)d_in[10];
  const float* bih0 = (const float*)d_in[11];
  const float* bhh0 = (const float*)d_in[12];
  const float* Wih1 = (const float*)d_in[13];
  const float* Whh1 = (const float*)d_in[14];
  const float* bih1 = (const float*)d_in[15];
  const float* bhh1 = (const float*)d_in[16];
  const float* W3   = (const float*)d_in[17];
  const float* b3   = (const float*)d_in[18];
  const float* W4   = (const float*)d_in[19];
  const float* b4   = (const float*)d_in[20];

  short* wsb = (short*)d_ws;
  float* xpg = (float*)((char*)d_ws + XP_OFF);

  prep_kernel<<<4232, 256, 0, stream>>>(Wih0, Whh0, Wih1, Whh1, W3, W4, wsb);
  curve_main<<<64, 512, 0, stream>>>(x, W1, b1, g1, be1, W2, b2, g2, be2,
                                     bih0, bhh0, bih1, bhh1, b3, b4, wsb, xpg,
                                     (float*)d_out);
}